// Round 5
// baseline (994.918 us; speedup 1.0000x reference)
//
#include <hip/hip_runtime.h>

// ---------------------------------------------------------------------------
// TTT layer forward: B=4, L=8192, D=1024, H=16, HD=64, C=64, NC=128
// ---------------------------------------------------------------------------

typedef __attribute__((ext_vector_type(8))) short short8;
typedef __attribute__((ext_vector_type(4))) short short4v;
typedef __attribute__((ext_vector_type(4))) float f32x4;
typedef __attribute__((ext_vector_type(4))) unsigned short us4;

__device__ __forceinline__ float bf2f(unsigned short s) {
  union { unsigned int u; float f; } c;
  c.u = ((unsigned int)s) << 16;
  return c.f;
}
__device__ __forceinline__ unsigned short f2bf(float f) {
  union { float f; unsigned int u; } c;
  c.f = f;
  unsigned int u = c.u;
  return (unsigned short)((u + 0x7FFFu + ((u >> 16) & 1u)) >> 16);
}

__device__ __forceinline__ void gload_lds16(const void* g, void* l) {
  __builtin_amdgcn_global_load_lds(
      (const __attribute__((address_space(1))) unsigned int*)g,
      (__attribute__((address_space(3))) unsigned int*)l, 16, 0, 0);
}

__device__ __forceinline__ float dpp16_sum(float x) {
  int v = __float_as_int(x);
  x += __int_as_float(__builtin_amdgcn_update_dpp(v, v, 0xB1, 0xF, 0xF, true));
  v = __float_as_int(x);
  x += __int_as_float(__builtin_amdgcn_update_dpp(v, v, 0x4E, 0xF, 0xF, true));
  v = __float_as_int(x);
  x += __int_as_float(__builtin_amdgcn_update_dpp(v, v, 0x141, 0xF, 0xF, true));
  v = __float_as_int(x);
  x += __int_as_float(__builtin_amdgcn_update_dpp(v, v, 0x140, 0xF, 0xF, true));
  return x;
}
// 8-lane sum (xor 1,2,4)
__device__ __forceinline__ float sum8(float x) {
  x += __shfl_xor(x, 1);
  x += __shfl_xor(x, 2);
  x += __shfl_xor(x, 4);
  return x;
}

__device__ __forceinline__ void barrier_fast() {
  __builtin_amdgcn_sched_barrier(0);
  asm volatile("s_waitcnt lgkmcnt(0)" ::: "memory");
  __builtin_amdgcn_s_barrier();
  asm volatile("" ::: "memory");
  __builtin_amdgcn_sched_barrier(0);
}
__device__ __forceinline__ void bar_nowait() {
  __builtin_amdgcn_sched_barrier(0);
  asm volatile("" ::: "memory");
  __builtin_amdgcn_s_barrier();
  asm volatile("" ::: "memory");
  __builtin_amdgcn_sched_barrier(0);
}

// ---------------- conversion kernels ----------------
__global__ __launch_bounds__(256) void cvt_f32_bf16(
    const float* __restrict__ in, unsigned short* __restrict__ out, long n) {
  long i = ((long)blockIdx.x * 256 + threadIdx.x) * 4;
  if (i + 3 < n) {
    float4 v = *(const float4*)&in[i];
    us4 o = { f2bf(v.x), f2bf(v.y), f2bf(v.z), f2bf(v.w) };
    *(us4*)&out[i] = o;
  }
}

__global__ __launch_bounds__(256) void build_wcat(
    const float* __restrict__ wq, const float* __restrict__ wk,
    const float* __restrict__ wv, const float* __restrict__ lrw,
    const float* __restrict__ wqb, const float* __restrict__ wkb,
    const float* __restrict__ wvb, const float* __restrict__ lrb,
    unsigned short* __restrict__ Wcat, float* __restrict__ biasc) {
  int i = blockIdx.x * 256 + threadIdx.x;  // 0 .. 3328*1024-1
  int row = i >> 10, col = i & 1023;
  float v;
  if (row < 1024)      v = wq[i];
  else if (row < 2048) v = wk[i - 1048576];
  else if (row < 3072) v = wv[i - 2097152];
  else if (row < 3088) v = lrw[(row - 3072) * 1024 + col];
  else                 v = 0.f;
  Wcat[i] = f2bf(v);
  if (i < 3328) {
    float bv;
    if (i < 1024)      bv = wqb[i];
    else if (i < 2048) bv = wkb[i - 1024];
    else if (i < 3072) bv = wvb[i - 2048];
    else if (i < 3088) bv = lrb[i - 3072];
    else               bv = 0.f;
    biasc[i] = bv;
  }
}

// ---------------- 256x256 8-wave GEMM: C = A[M,K] @ B[N,K]^T + bias ----------
template <int WRITE_BF16>
__global__ __launch_bounds__(512, 1) void gemm256(
    const unsigned short* __restrict__ A, const unsigned short* __restrict__ B,
    const float* __restrict__ bias, void* __restrict__ Cout,
    long M, long N, long K, int NTILN, long ldc) {
  __shared__ __align__(16) unsigned short g_lds[65536];  // 128 KB
  char* ldsc = (char*)g_lds;
  const int tid = threadIdx.x, lane = tid & 63, wid = tid >> 6;
  const int wm = wid >> 2, wn = wid & 3;
  const int l15 = lane & 15, lg = lane >> 4;

  unsigned nwg = gridDim.x, bid = blockIdx.x;
  unsigned cpx = nwg >> 3;
  unsigned swz = (bid & 7) * cpx + (bid >> 3);
  unsigned nidx = swz % (unsigned)NTILN, midx = swz / (unsigned)NTILN;
  const long m0 = (long)midx * 256, n0 = (long)nidx * 256;
  const long ldab = K * 2;

  const int srow = wid * 16 + (lane >> 2);
  const int scol = ((lane & 3) * 16) ^ (((lane >> 3) & 3) << 4);
  const int sdst = wid * 1024;
  const char* Ab = (const char*)A;
  const char* Bb = (const char*)B;

  const int acol = (lg * 16) ^ (((l15 >> 1) & 3) << 4);
  const int aro = (wm * 128 + l15) * 64 + acol;
  const int bro = 65536 + (wn * 64 + l15) * 64 + acol;

#define STG_A(tt, h, bb)                                                      \
  gload_lds16(Ab + (size_t)(m0 + (h) * 128 + srow) * ldab + (size_t)(tt) * 64 \
                  + scol,                                                     \
              ldsc + (bb) * 16384 + (h) * 8192 + sdst)
#define STG_B(tt, h, bb)                                                      \
  gload_lds16(Bb + (size_t)(n0 + (h) * 128 + srow) * ldab + (size_t)(tt) * 64 \
                  + scol,                                                     \
              ldsc + 65536 + (bb) * 16384 + (h) * 8192 + sdst)

  f32x4 acc[8][4];
#pragma unroll
  for (int m = 0; m < 8; ++m)
#pragma unroll
    for (int n = 0; n < 4; ++n) acc[m][n] = (f32x4){0.f, 0.f, 0.f, 0.f};

  const int NT = (int)(K >> 5);

#pragma unroll
  for (int tt = 0; tt < 3; ++tt) {
    STG_A(tt, 0, tt); STG_A(tt, 1, tt);
    STG_B(tt, 0, tt); STG_B(tt, 1, tt);
  }
  asm volatile("s_waitcnt vmcnt(8)" ::: "memory");
  bar_nowait();

#pragma unroll 1
  for (int t = 0; t < NT; ++t) {
    const int buf = t & 3, sb = (t + 3) & 3;
    const bool doStage = (t + 3 < NT);
    const char* ab = ldsc + buf * 16384 + aro;
    const char* bb = ldsc + buf * 16384 + bro;

    short8 av[4], bv[4];
#pragma unroll
    for (int i = 0; i < 4; ++i) av[i] = *(const short8*)(ab + i * 1024);
#pragma unroll
    for (int nf = 0; nf < 4; ++nf) bv[nf] = *(const short8*)(bb + nf * 1024);
    if (doStage) { STG_A(t + 3, 0, sb); STG_A(t + 3, 1, sb); }
    bar_nowait();
    __builtin_amdgcn_s_setprio(1);
#pragma unroll
    for (int i = 0; i < 4; ++i)
#pragma unroll
      for (int nf = 0; nf < 4; ++nf)
        acc[i][nf] = __builtin_amdgcn_mfma_f32_16x16x32_bf16(av[i], bv[nf],
                                                             acc[i][nf], 0, 0, 0);
    __builtin_amdgcn_s_setprio(0);
    bar_nowait();

#pragma unroll
    for (int i = 0; i < 4; ++i) av[i] = *(const short8*)(ab + 4096 + i * 1024);
    if (doStage) { STG_B(t + 3, 0, sb); STG_B(t + 3, 1, sb); }
    bar_nowait();
    __builtin_amdgcn_s_setprio(1);
#pragma unroll
    for (int i = 0; i < 4; ++i)
#pragma unroll
      for (int nf = 0; nf < 4; ++nf)
        acc[4 + i][nf] = __builtin_amdgcn_mfma_f32_16x16x32_bf16(
            av[i], bv[nf], acc[4 + i][nf], 0, 0, 0);
    __builtin_amdgcn_s_setprio(0);
    asm volatile("s_waitcnt vmcnt(8)" ::: "memory");
    bar_nowait();
  }
#undef STG_A
#undef STG_B

#pragma unroll
  for (int mf = 0; mf < 8; ++mf) {
    long r0 = m0 + wm * 128 + mf * 16 + lg * 4;
#pragma unroll
    for (int nf = 0; nf < 4; ++nf) {
      long c = n0 + wn * 64 + nf * 16 + l15;
      float bvv = bias ? bias[c] : 0.f;
#pragma unroll
      for (int j = 0; j < 4; ++j) {
        float v = acc[mf][nf][j] + bvv;
        if (WRITE_BF16)
          ((unsigned short*)Cout)[(r0 + j) * ldc + c] = f2bf(v);
        else
          ((float*)Cout)[(r0 + j) * ldc + c] = v;
      }
    }
  }
}

// ---------------- TTT scan with fused stage2 ----------------
// One block per (b,h) chain: 8 waves, role-split, 2 raw barriers per chunk.
// Staging reads QKVL directly and computes l2norm(q), l2norm(k),
// tgt = LN_ddof1(v-kn), eta = sigmoid(lr)/4096 inline (off critical path).
__global__ __launch_bounds__(512, 1) void ttt_scan(
    const unsigned short* __restrict__ QKVL, const float* __restrict__ W1,
    const float* __restrict__ b1, const float* __restrict__ tnw,
    const float* __restrict__ tnb, unsigned short* __restrict__ y) {
  const int bh = blockIdx.x;
  const int b = bh >> 4, h = bh & 15;
  const int tid = threadIdx.x;
  const int lane = tid & 63, wid = tid >> 6;
  const bool isA = wid < 4;
  const int q = wid & 3;
  const int l15 = lane & 15, lg = lane >> 4;

  __shared__ __align__(16) unsigned short xq_s[2][64 * 72];
  __shared__ __align__(16) unsigned short tg_s[2][64 * 72];
  __shared__ __align__(16) unsigned short xk_s[2][64 * 72];
  __shared__ __align__(16) unsigned short gc_s[64 * 72];
  __shared__ __align__(16) unsigned short gradT[64 * 72];
  __shared__ __align__(16) unsigned short WT_b[2][64 * 72];
  __shared__ __align__(16) unsigned short xkTe[64 * 68];  // stride 68: 4-way max
  __shared__ float eta_s[2][64];
  __shared__ float bpart[4][64];

  const size_t tokb = (size_t)b * 8192;
  const int col0 = h * 64;
  const size_t qcol = (size_t)h * 64;
  const size_t kcol = 1024 + (size_t)h * 64;
  const size_t vcol = 2048 + (size_t)h * 64;
  const size_t lcol = 3072 + (size_t)h;
  const int rr_ = q * 16 + (lane >> 3);  // +j*8
  const int c8_ = (lane & 7) * 8;

  short8 pQ[2], pK[2], pV[2];
  unsigned short plr = 0;
  float bstv[4], gwv[4], gbv[4], P0 = 0.f;
  float twB[8], tbB[8];
  f32x4 Wreg[4];

  // ---- commit helpers (normalization fused into staging) ----
  auto commitA = [&](int bb) {
#pragma unroll
    for (int j = 0; j < 2; ++j) {
      float f[8], s = 0.f;
#pragma unroll
      for (int u = 0; u < 8; ++u) {
        f[u] = bf2f((unsigned short)pQ[j][u]);
        s += f[u] * f[u];
      }
      s = sum8(s);
      float rn = 1.f / fmaxf(sqrtf(s), 1e-12f);
      short8 o;
#pragma unroll
      for (int u = 0; u < 8; ++u) o[u] = (short)f2bf(f[u] * rn);
      *(short8*)&xq_s[bb][(rr_ + j * 8) * 72 + c8_] = o;
    }
  };
  auto commitB = [&](int bb) {
#pragma unroll
    for (int j = 0; j < 2; ++j) {
      float kf[8], vf[8];
      float sk2 = 0.f, sk1 = 0.f, sv1 = 0.f, sv2 = 0.f, svk = 0.f;
#pragma unroll
      for (int u = 0; u < 8; ++u) {
        kf[u] = bf2f((unsigned short)pK[j][u]);
        vf[u] = bf2f((unsigned short)pV[j][u]);
        sk2 += kf[u] * kf[u];
        sk1 += kf[u];
        sv1 += vf[u];
        sv2 += vf[u] * vf[u];
        svk += vf[u] * kf[u];
      }
      sk2 = sum8(sk2); sk1 = sum8(sk1); sv1 = sum8(sv1);
      sv2 = sum8(sv2); svk = sum8(svk);
      float rsk = 1.f / fmaxf(sqrtf(sk2), 1e-12f);
      float mu = (sv1 - rsk * sk1) * 0.015625f;
      float d2 = sv2 - 2.f * rsk * svk + rsk * rsk * sk2;
      float var1 = fmaxf(d2 - 64.f * mu * mu, 0.f) * (1.f / 63.f);
      float rs = 1.f / (sqrtf(var1) + 1e-5f);
      short8 ok, ot;
#pragma unroll
      for (int u = 0; u < 8; ++u) {
        float kn = kf[u] * rsk;
        float tg = twB[u] * ((vf[u] - kn - mu) * rs) + tbB[u];
        ok[u] = (short)f2bf(kn);
        ot[u] = (short)f2bf(tg);
      }
      *(short8*)&xk_s[bb][(rr_ + j * 8) * 72 + c8_] = ok;
      *(short8*)&tg_s[bb][(rr_ + j * 8) * 72 + c8_] = ot;
    }
    if (wid == 4) {
      float lgt = bf2f(plr);
      eta_s[bb][lane] = (1.f / 4096.f) / (1.f + __expf(-lgt));
    }
  };

  // ---- prologue ----
  if (isA) {
#pragma unroll
    for (int j = 0; j < 2; ++j)
      pQ[j] = *(const short8*)&QKVL[(tokb + rr_ + j * 8) * 3328 + qcol + c8_];
#pragma unroll
    for (int n = 0; n < 4; ++n) {
      int e = n * 16 + l15;
      bstv[n] = b1[h * 64 + e];
      gwv[n] = tnw[h * 64 + e];
      gbv[n] = tnb[h * 64 + e];
      P0 += gwv[n] * gwv[n];
    }
    P0 = dpp16_sum(P0);
    commitA(0);
#pragma unroll
    for (int j = 0; j < 2; ++j)
      pQ[j] = *(const short8*)&QKVL[(tokb + 64 + rr_ + j * 8) * 3328 + qcol + c8_];
  } else {
#pragma unroll
    for (int j = 0; j < 2; ++j) {
      pK[j] = *(const short8*)&QKVL[(tokb + rr_ + j * 8) * 3328 + kcol + c8_];
      pV[j] = *(const short8*)&QKVL[(tokb + rr_ + j * 8) * 3328 + vcol + c8_];
    }
    if (wid == 4) plr = QKVL[(tokb + lane) * 3328 + lcol];
#pragma unroll
    for (int u = 0; u < 4; ++u) {
      twB[u] = tnw[h * 64 + c8_ + u];
      twB[u + 4] = tnw[h * 64 + c8_ + 4 + u];
      tbB[u] = tnb[h * 64 + c8_ + u];
      tbB[u + 4] = tnb[h * 64 + c8_ + 4 + u];
    }
#pragma unroll
    for (int n = 0; n < 4; ++n)
#pragma unroll
      for (int jj = 0; jj < 4; ++jj) {
        int d = q * 16 + lg * 4 + jj, e = n * 16 + l15;
        float w = W1[h * 4096 + d * 64 + e];
        Wreg[n][jj] = w;
        WT_b[0][e * 72 + d] = f2bf(w);
      }
    commitB(0);
#pragma unroll
    for (int j = 0; j < 2; ++j) {
      pK[j] = *(const short8*)&QKVL[(tokb + 64 + rr_ + j * 8) * 3328 + kcol + c8_];
      pV[j] = *(const short8*)&QKVL[(tokb + 64 + rr_ + j * 8) * 3328 + vcol + c8_];
    }
    if (wid == 4) plr = QKVL[(tokb + 64 + lane) * 3328 + lcol];
  }
  __syncthreads();

  for (int nc = 0; nc < 128; ++nc) {
    const int p = nc & 1;
    const unsigned short* WTc = WT_b[p];
    unsigned short* WTn = WT_b[p ^ 1];

    // ================= phase 1 =================
    if (isA) {
      // frag + tgt reads issue first (latency hides under MFMA/commit)
      short8 a_xk[2], b_w[2][4];
#pragma unroll
      for (int kk = 0; kk < 2; ++kk) {
        const int ko = kk * 32 + lg * 8;
        a_xk[kk] = *(const short8*)&xk_s[p][(q * 16 + l15) * 72 + ko];
#pragma unroll
        for (int n = 0; n < 4; ++n)
          b_w[kk][n] = *(const short8*)&WTc[(n * 16 + l15) * 72 + ko];
      }
      float tval[4][4];
#pragma unroll
      for (int j = 0; j < 4; ++j) {
        const int r = q * 16 + lg * 4 + j;
#pragma unroll
        for (int n = 0; n < 4; ++n)
          tval[j][n] = bf2f(tg_s[p][r * 72 + n * 16 + l15]);
      }
      float etar[4];
#pragma unroll
      for (int j = 0; j < 4; ++j) etar[j] = eta_s[p][q * 16 + lg * 4 + j];

      f32x4 accZ[4];
#pragma unroll
      for (int n = 0; n < 4; ++n)
        accZ[n] = (f32x4){bstv[n], bstv[n], bstv[n], bstv[n]};
      __builtin_amdgcn_s_setprio(1);
#pragma unroll
      for (int kk = 0; kk < 2; ++kk)
#pragma unroll
        for (int n = 0; n < 4; ++n)
          accZ[n] = __builtin_amdgcn_mfma_f32_16x16x32_bf16(a_xk[kk], b_w[kk][n],
                                                            accZ[n], 0, 0, 0);
      __builtin_amdgcn_s_setprio(0);

      // overlap under MFMA latency: commit next chunk + prefetch nc+2
      if (nc + 1 < 128) commitA(p ^ 1);
      if (nc + 2 < 128) {
#pragma unroll
        for (int j = 0; j < 2; ++j)
          pQ[j] = *(const short8*)
              &QKVL[(tokb + (nc + 2) * 64 + rr_ + j * 8) * 3328 + qcol + c8_];
      }

      // LN-l2 backward: single fused reduction round (6 parallel sums)
      float grv[4][4];
      float bl[4] = {0.f, 0.f, 0.f, 0.f};
#pragma unroll
      for (int j = 0; j < 4; ++j) {
        float z[4], cn[4];
        float a1 = 0.f, a2 = 0.f, p1 = 0.f, p2 = 0.f, q0 = 0.f, q1 = 0.f;
#pragma unroll
        for (int n = 0; n < 4; ++n) {
          z[n] = accZ[n][j];
          float g = gwv[n];
          float g2 = g * g;
          cn[n] = g * (gbv[n] - tval[j][n]);
          a1 += z[n];
          a2 += z[n] * z[n];
          p1 += g2 * z[n];
          p2 += g2 * z[n] * z[n];
          q0 += cn[n];
          q1 += cn[n] * z[n];
        }
        a1 = dpp16_sum(a1);
        a2 = dpp16_sum(a2);
        p1 = dpp16_sum(p1);
        p2 = dpp16_sum(p2);
        q0 = dpp16_sum(q0);
        q1 = dpp16_sum(q1);
        float mu = a1 * 0.015625f;
        float var = a2 * 0.015625f - mu * mu;
        float rstd = rsqrtf(var + 1e-6f);
        float S3 = rstd * (p1 - mu * P0) + q0;
        float S4 = rstd * rstd * (p2 - 2.f * mu * p1 + mu * mu * P0) +
                   rstd * (q1 - mu * q0);
        float rs64 = rstd * 0.015625f;
#pragma unroll
        for (int n = 0; n < 4; ++n) {
          float xh = (z[n] - mu) * rstd;
          float gx = gwv[n] * gwv[n] * xh + cn[n];
          float gr = (64.f * gx - S3 - xh * S4) * rs64;
          grv[n][j] = gr;
          bl[n] += etar[j] * gr;
        }
      }
#pragma unroll
      for (int n = 0; n < 4; ++n) {
        us4 pk = {f2bf(grv[n][0]), f2bf(grv[n][1]), f2bf(grv[n][2]),
                  f2bf(grv[n][3])};
        *(us4*)&gradT[(n * 16 + l15) * 72 + q * 16 + lg * 4] = pk;
        // bpart: reduce over lg groups (rows of this wave)
        float s = bl[n];
        s += __shfl_xor(s, 16);
        s += __shfl_xor(s, 32);
        if (lg == 0) bpart[q][n * 16 + l15] = s;
      }
    } else {
      // B: frag reads first
      short8 a_xq[2], b_k[2][4];
#pragma unroll
      for (int kk = 0; kk < 2; ++kk) {
        const int ko = kk * 32 + lg * 8;
        a_xq[kk] = *(const short8*)&xq_s[p][(q * 16 + l15) * 72 + ko];
#pragma unroll
        for (int n = 0; n < 4; ++n)
          b_k[kk][n] = *(const short8*)&xk_s[p][(n * 16 + l15) * 72 + ko];
      }
      f32x4 accA[4];
#pragma unroll
      for (int n = 0; n < 4; ++n) accA[n] = (f32x4){0.f, 0.f, 0.f, 0.f};
      __builtin_amdgcn_s_setprio(1);
#pragma unroll
      for (int kk = 0; kk < 2; ++kk)
#pragma unroll
        for (int n = 0; n < 4; ++n)
          accA[n] = __builtin_amdgcn_mfma_f32_16x16x32_bf16(a_xq[kk], b_k[kk][n],
                                                            accA[n], 0, 0, 0);
      __builtin_amdgcn_s_setprio(0);

      // xkTe[d][c] = -eta[c]*xk[c][d]  (stride-68 buffer)
#pragma unroll
      for (int it = 0; it < 4; ++it) {
        int c0 = q * 16 + it * 4;
        us4 pk;
#pragma unroll
        for (int u = 0; u < 4; ++u)
          pk[u] = f2bf(-eta_s[p][c0 + u] * bf2f(xk_s[p][(c0 + u) * 72 + lane]));
        *(us4*)&xkTe[lane * 68 + c0] = pk;
      }

      if (nc + 1 < 128) commitB(p ^ 1);
      if (nc + 2 < 128) {
#pragma unroll
        for (int j = 0; j < 2; ++j) {
          pK[j] = *(const short8*)
              &QKVL[(tokb + (nc + 2) * 64 + rr_ + j * 8) * 3328 + kcol + c8_];
          pV[j] = *(const short8*)
              &QKVL[(tokb + (nc + 2) * 64 + rr_ + j * 8) * 3328 + vcol + c8_];
        }
        if (wid == 4) plr = QKVL[(tokb + (nc + 2) * 64 + lane) * 3328 + lcol];
      }

#pragma unroll
      for (int j = 0; j < 4; ++j) {
        const int r = q * 16 + lg * 4 + j;
#pragma unroll
        for (int n = 0; n < 4; ++n) {
          int cj = n * 16 + l15;
          float v = (cj <= r) ? (-eta_s[p][cj] * (1.f + accA[n][j])) : 0.f;
          gc_s[r * 72 + cj] = f2bf(v);
        }
      }
    }
    barrier_fast();  // X

    // ================= phase 2 =================
    if (isA) {
      short8 a_xq[2], a_gc[2], b_w[2][4], b_g[2][4];
#pragma unroll
      for (int kk = 0; kk < 2; ++kk) {
        const int ko = kk * 32 + lg * 8;
        a_xq[kk] = *(const short8*)&xq_s[p][(q * 16 + l15) * 72 + ko];
        a_gc[kk] = *(const short8*)&gc_s[(q * 16 + l15) * 72 + ko];
#pragma unroll
        for (int n = 0; n < 4; ++n) {
          b_w[kk][n] = *(const short8*)&WTc[(n * 16 + l15) * 72 + ko];
          b_g[kk][n] = *(const short8*)&gradT[(n * 16 + l15) * 72 + ko];
        }
      }
      f32x4 accZb[4];
#pragma unroll
      for (int n = 0; n < 4; ++n)
        accZb[n] = (f32x4){bstv[n], bstv[n], bstv[n], bstv[n]};
      __builtin_amdgcn_s_setprio(1);
#pragma unroll
      for (int kk = 0; kk < 2; ++kk)
#pragma unroll
        for (int n = 0; n < 4; ++n) {
          accZb[n] = __builtin_amdgcn_mfma_f32_16x16x32_bf16(a_xq[kk], b_w[kk][n],
                                                             accZb[n], 0, 0, 0);
          accZb[n] = __builtin_amdgcn_mfma_f32_16x16x32_bf16(a_gc[kk], b_g[kk][n],
                                                             accZb[n], 0, 0, 0);
        }
      __builtin_amdgcn_s_setprio(0);

      // b update (off critical path, overlaps MFMA latency)
#pragma unroll
      for (int n = 0; n < 4; ++n) {
        int e = n * 16 + l15;
        bstv[n] -= bpart[0][e] + bpart[1][e] + bpart[2][e] + bpart[3][e];
      }

#pragma unroll
      for (int j = 0; j < 4; ++j) {
        const int r = q * 16 + lg * 4 + j;
        float z[4], s1 = 0.f, s2 = 0.f;
#pragma unroll
        for (int n = 0; n < 4; ++n) {
          z[n] = accZb[n][j];
          s1 += z[n];
          s2 += z[n] * z[n];
        }
        s1 = dpp16_sum(s1);
        s2 = dpp16_sum(s2);
        float mu = s1 * 0.015625f;
        float var = s2 * 0.015625f - mu * mu;
        float rstd = rsqrtf(var + 1e-6f);
        size_t gbase = (tokb + nc * 64 + r) * 1024 + col0;
#pragma unroll
        for (int n = 0; n < 4; ++n) {
          int e = n * 16 + l15;
          float ov = bf2f(xq_s[p][r * 72 + e]) + gwv[n] * ((z[n] - mu) * rstd) + gbv[n];
          y[gbase + e] = f2bf(ov);
        }
      }
    } else {
      short8 a_ke[2], b_g[2][4];
#pragma unroll
      for (int kk = 0; kk < 2; ++kk) {
        const int ko = kk * 32 + lg * 8;
        short4v lo = *(const short4v*)&xkTe[(q * 16 + l15) * 68 + ko];
        short4v hi = *(const short4v*)&xkTe[(q * 16 + l15) * 68 + ko + 4];
        a_ke[kk] = (short8){lo[0], lo[1], lo[2], lo[3], hi[0], hi[1], hi[2], hi[3]};
#pragma unroll
        for (int n = 0; n < 4; ++n)
          b_g[kk][n] = *(const short8*)&gradT[(n * 16 + l15) * 72 + ko];
      }
      f32x4 accW[4];
#pragma unroll
      for (int n = 0; n < 4; ++n) accW[n] = Wreg[n];
      __builtin_amdgcn_s_setprio(1);
#pragma unroll
      for (int kk = 0; kk < 2; ++kk)
#pragma unroll
        for (int n = 0; n < 4; ++n)
          accW[n] = __builtin_amdgcn_mfma_f32_16x16x32_bf16(a_ke[kk], b_g[kk][n],
                                                            accW[n], 0, 0, 0);
      __builtin_amdgcn_s_setprio(0);
#pragma unroll
      for (int n = 0; n < 4; ++n) {
        Wreg[n] = accW[n];
        us4 pk = {f2bf(accW[n][0]), f2bf(accW[n][1]), f2bf(accW[n][2]),
                  f2bf(accW[n][3])};
        *(us4*)&WTn[(n * 16 + l15) * 72 + q * 16 + lg * 4] = pk;
      }
    }
    barrier_fast();  // Y
  }
}

// ---------------- stage 4: post layernorm over D=1024 (bf16 in) ----------------
__global__ __launch_bounds__(256) void postnorm(
    const unsigned short* __restrict__ yv, const float* __restrict__ pw,
    const float* __restrict__ pb, unsigned short* __restrict__ yn) {
  int t = blockIdx.x;
  int tid = threadIdx.x, lane = tid & 63, wid = tid >> 6;
  us4 v4 = *(const us4*)&yv[(size_t)t * 1024 + tid * 4];
  float v[4];
  float s1 = 0.f, s2 = 0.f;
#pragma unroll
  for (int u = 0; u < 4; ++u) {
    v[u] = bf2f(v4[u]);
    s1 += v[u];
    s2 += v[u] * v[u];
  }
#pragma unroll
  for (int o = 1; o < 64; o <<= 1) {
    s1 += __shfl_xor(s1, o);
    s2 += __shfl_xor(s2, o);
  }
  __shared__ float r1[4], r2[4];
  if (lane == 0) {
    r1[wid] = s1;
    r2[wid] = s2;
  }
  __syncthreads();
  s1 = r1[0] + r1[1] + r1[2] + r1[3];
  s2 = r2[0] + r2[1] + r2[2] + r2[3];
  float mu = s1 * (1.f / 1024.f);
  float var = s2 * (1.f / 1024.f) - mu * mu;
  float rstd = rsqrtf(var + 1e-6f);
  int c = tid * 4;
  us4 o4;
#pragma unroll
  for (int u = 0; u < 4; ++u)
    o4[u] = f2bf(pw[c + u] * ((v[u] - mu) * rstd) + pb[c + u]);
  *(us4*)&yn[(size_t)t * 1024 + c] = o4;
}

// ---------------------------------------------------------------------------
extern "C" void kernel_launch(void* const* d_in, const int* in_sizes, int n_in,
                              void* d_out, int out_size, void* d_ws,
                              size_t ws_size, hipStream_t stream) {
  const float* hs  = (const float*)d_in[0];
  const float* wqw = (const float*)d_in[1];
  const float* wqb = (const float*)d_in[2];
  const float* wkw = (const float*)d_in[3];
  const float* wkb = (const float*)d_in[4];
  const float* wvw = (const float*)d_in[5];
  const float* wvb = (const float*)d_in[6];
  const float* wow = (const float*)d_in[7];
  const float* wob = (const float*)d_in[8];
  const float* tnw = (const float*)d_in[9];
  const float* tnb = (const float*)d_in[10];
  const float* lrw = (const float*)d_in[11];
  const float* lrb = (const float*)d_in[12];
  const float* W1  = (const float*)d_in[13];
  const float* b1  = (const float*)d_in[14];
  const float* pnw = (const float*)d_in[15];
  const float* pnb = (const float*)d_in[16];

  // workspace: [hs_bf 64M | Wcat 6.6M | biasc | wo_bf 2M | QKVL 218M | ynorm 64M]
  // y (bf16, 64M) aliases hs_bf (dead after QKV GEMM).
  const size_t OFF_WCAT  = 67108864;
  const size_t OFF_BIASC = OFF_WCAT + 6815744;
  const size_t OFF_WOBF  = OFF_BIASC + 16384;
  const size_t OFF_QKVL  = OFF_WOBF + 2097152;
  const size_t OFF_YN    = OFF_QKVL + 218103808;
  const size_t NEEDED    = OFF_YN + 67108864;
  if (ws_size < NEEDED) return;

  char* ws = (char*)d_ws;
  unsigned short* hs_bf = (unsigned short*)ws;
  unsigned short* ybf   = (unsigned short*)ws;              // alias (after gemm)
  unsigned short* Wcat  = (unsigned short*)(ws + OFF_WCAT);
  float* biasc          = (float*)(ws + OFF_BIASC);
  unsigned short* wo_bf = (unsigned short*)(ws + OFF_WOBF);
  unsigned short* QKVL  = (unsigned short*)(ws + OFF_QKVL);
  unsigned short* ynorm = (unsigned short*)(ws + OFF_YN);

  cvt_f32_bf16<<<32768, 256, 0, stream>>>(hs, hs_bf, 33554432L);
  build_wcat<<<13312, 256, 0, stream>>>(wqw, wkw, wvw, lrw, wqb, wkb, wvb, lrb,
                                        Wcat, biasc);
  cvt_f32_bf16<<<1024, 256, 0, stream>>>(wow, wo_bf, 1048576L);
  gemm256<1><<<1664, 512, 0, stream>>>(hs_bf, Wcat, biasc, QKVL,
                                       32768L, 3328L, 1024L, 13, 3328L);
  ttt_scan<<<64, 512, 0, stream>>>(QKVL, W1, b1, tnw, tnb, ybf);
  postnorm<<<32768, 256, 0, stream>>>(ybf, pnw, pnb, ynorm);
  gemm256<0><<<512, 512, 0, stream>>>(ynorm, wo_bf, wob, d_out,
                                      32768L, 1024L, 1024L, 4, 1024L);
}

// Round 6
// 977.808 us; speedup vs baseline: 1.0175x; 1.0175x over previous
//
#include <hip/hip_runtime.h>

// ---------------------------------------------------------------------------
// TTT layer forward: B=4, L=8192, D=1024, H=16, HD=64, C=64, NC=128
// ---------------------------------------------------------------------------

typedef __attribute__((ext_vector_type(8))) short short8;
typedef __attribute__((ext_vector_type(4))) short short4v;
typedef __attribute__((ext_vector_type(4))) float f32x4;
typedef __attribute__((ext_vector_type(4))) unsigned short us4;

__device__ __forceinline__ float bf2f(unsigned short s) {
  union { unsigned int u; float f; } c;
  c.u = ((unsigned int)s) << 16;
  return c.f;
}
__device__ __forceinline__ unsigned short f2bf(float f) {
  union { float f; unsigned int u; } c;
  c.f = f;
  unsigned int u = c.u;
  return (unsigned short)((u + 0x7FFFu + ((u >> 16) & 1u)) >> 16);
}

__device__ __forceinline__ void gload_lds16(const void* g, void* l) {
  __builtin_amdgcn_global_load_lds(
      (const __attribute__((address_space(1))) unsigned int*)g,
      (__attribute__((address_space(3))) unsigned int*)l, 16, 0, 0);
}

__device__ __forceinline__ float dpp16_sum(float x) {
  int v = __float_as_int(x);
  x += __int_as_float(__builtin_amdgcn_update_dpp(v, v, 0xB1, 0xF, 0xF, true));
  v = __float_as_int(x);
  x += __int_as_float(__builtin_amdgcn_update_dpp(v, v, 0x4E, 0xF, 0xF, true));
  v = __float_as_int(x);
  x += __int_as_float(__builtin_amdgcn_update_dpp(v, v, 0x141, 0xF, 0xF, true));
  v = __float_as_int(x);
  x += __int_as_float(__builtin_amdgcn_update_dpp(v, v, 0x140, 0xF, 0xF, true));
  return x;
}

__device__ __forceinline__ void barrier_fast() {
  __builtin_amdgcn_sched_barrier(0);
  asm volatile("s_waitcnt lgkmcnt(0)" ::: "memory");
  __builtin_amdgcn_s_barrier();
  asm volatile("" ::: "memory");
  __builtin_amdgcn_sched_barrier(0);
}
__device__ __forceinline__ void bar_nowait() {
  __builtin_amdgcn_sched_barrier(0);
  asm volatile("" ::: "memory");
  __builtin_amdgcn_s_barrier();
  asm volatile("" ::: "memory");
  __builtin_amdgcn_sched_barrier(0);
}

// ---------------- conversion kernels ----------------
__global__ __launch_bounds__(256) void cvt_f32_bf16(
    const float* __restrict__ in, unsigned short* __restrict__ out, long n) {
  long i = ((long)blockIdx.x * 256 + threadIdx.x) * 4;
  if (i + 3 < n) {
    float4 v = *(const float4*)&in[i];
    us4 o = { f2bf(v.x), f2bf(v.y), f2bf(v.z), f2bf(v.w) };
    *(us4*)&out[i] = o;
  }
}

__global__ __launch_bounds__(256) void build_wcat(
    const float* __restrict__ wq, const float* __restrict__ wk,
    const float* __restrict__ wv, const float* __restrict__ lrw,
    const float* __restrict__ wqb, const float* __restrict__ wkb,
    const float* __restrict__ wvb, const float* __restrict__ lrb,
    unsigned short* __restrict__ Wcat, float* __restrict__ biasc) {
  int i = blockIdx.x * 256 + threadIdx.x;  // 0 .. 3328*1024-1
  int row = i >> 10, col = i & 1023;
  float v;
  if (row < 1024)      v = wq[i];
  else if (row < 2048) v = wk[i - 1048576];
  else if (row < 3072) v = wv[i - 2097152];
  else if (row < 3088) v = lrw[(row - 3072) * 1024 + col];
  else                 v = 0.f;
  Wcat[i] = f2bf(v);
  if (i < 3328) {
    float bv;
    if (i < 1024)      bv = wqb[i];
    else if (i < 2048) bv = wkb[i - 1024];
    else if (i < 3072) bv = wvb[i - 2048];
    else if (i < 3088) bv = lrb[i - 3072];
    else               bv = 0.f;
    biasc[i] = bv;
  }
}

// ---------------- 256x256 8-wave GEMM: C = A[M,K] @ B[N,K]^T + bias ----------
template <int WRITE_BF16>
__global__ __launch_bounds__(512, 1) void gemm256(
    const unsigned short* __restrict__ A, const unsigned short* __restrict__ B,
    const float* __restrict__ bias, void* __restrict__ Cout,
    long M, long N, long K, int NTILN, long ldc) {
  __shared__ __align__(16) unsigned short g_lds[65536];  // 128 KB
  char* ldsc = (char*)g_lds;
  const int tid = threadIdx.x, lane = tid & 63, wid = tid >> 6;
  const int wm = wid >> 2, wn = wid & 3;
  const int l15 = lane & 15, lg = lane >> 4;

  unsigned nwg = gridDim.x, bid = blockIdx.x;
  unsigned cpx = nwg >> 3;
  unsigned swz = (bid & 7) * cpx + (bid >> 3);
  unsigned nidx = swz % (unsigned)NTILN, midx = swz / (unsigned)NTILN;
  const long m0 = (long)midx * 256, n0 = (long)nidx * 256;
  const long ldab = K * 2;

  const int srow = wid * 16 + (lane >> 2);
  const int scol = ((lane & 3) * 16) ^ (((lane >> 3) & 3) << 4);
  const int sdst = wid * 1024;
  const char* Ab = (const char*)A;
  const char* Bb = (const char*)B;

  const int acol = (lg * 16) ^ (((l15 >> 1) & 3) << 4);
  const int aro = (wm * 128 + l15) * 64 + acol;
  const int bro = 65536 + (wn * 64 + l15) * 64 + acol;

#define STG_A(tt, h, bb)                                                      \
  gload_lds16(Ab + (size_t)(m0 + (h) * 128 + srow) * ldab + (size_t)(tt) * 64 \
                  + scol,                                                     \
              ldsc + (bb) * 16384 + (h) * 8192 + sdst)
#define STG_B(tt, h, bb)                                                      \
  gload_lds16(Bb + (size_t)(n0 + (h) * 128 + srow) * ldab + (size_t)(tt) * 64 \
                  + scol,                                                     \
              ldsc + 65536 + (bb) * 16384 + (h) * 8192 + sdst)

  f32x4 acc[8][4];
#pragma unroll
  for (int m = 0; m < 8; ++m)
#pragma unroll
    for (int n = 0; n < 4; ++n) acc[m][n] = (f32x4){0.f, 0.f, 0.f, 0.f};

  const int NT = (int)(K >> 5);

#pragma unroll
  for (int tt = 0; tt < 3; ++tt) {
    STG_A(tt, 0, tt); STG_A(tt, 1, tt);
    STG_B(tt, 0, tt); STG_B(tt, 1, tt);
  }
  asm volatile("s_waitcnt vmcnt(8)" ::: "memory");
  bar_nowait();

#pragma unroll 1
  for (int t = 0; t < NT; ++t) {
    const int buf = t & 3, sb = (t + 3) & 3;
    const bool doStage = (t + 3 < NT);
    const char* ab = ldsc + buf * 16384 + aro;
    const char* bb = ldsc + buf * 16384 + bro;

    short8 av[4], bv[4];
#pragma unroll
    for (int i = 0; i < 4; ++i) av[i] = *(const short8*)(ab + i * 1024);
#pragma unroll
    for (int nf = 0; nf < 4; ++nf) bv[nf] = *(const short8*)(bb + nf * 1024);
    if (doStage) { STG_A(t + 3, 0, sb); STG_A(t + 3, 1, sb); }
    bar_nowait();
    __builtin_amdgcn_s_setprio(1);
#pragma unroll
    for (int i = 0; i < 4; ++i)
#pragma unroll
      for (int nf = 0; nf < 4; ++nf)
        acc[i][nf] = __builtin_amdgcn_mfma_f32_16x16x32_bf16(av[i], bv[nf],
                                                             acc[i][nf], 0, 0, 0);
    __builtin_amdgcn_s_setprio(0);
    bar_nowait();

#pragma unroll
    for (int i = 0; i < 4; ++i) av[i] = *(const short8*)(ab + 4096 + i * 1024);
    if (doStage) { STG_B(t + 3, 0, sb); STG_B(t + 3, 1, sb); }
    bar_nowait();
    __builtin_amdgcn_s_setprio(1);
#pragma unroll
    for (int i = 0; i < 4; ++i)
#pragma unroll
      for (int nf = 0; nf < 4; ++nf)
        acc[4 + i][nf] = __builtin_amdgcn_mfma_f32_16x16x32_bf16(
            av[i], bv[nf], acc[4 + i][nf], 0, 0, 0);
    __builtin_amdgcn_s_setprio(0);
    asm volatile("s_waitcnt vmcnt(8)" ::: "memory");
    bar_nowait();
  }
#undef STG_A
#undef STG_B

#pragma unroll
  for (int mf = 0; mf < 8; ++mf) {
    long r0 = m0 + wm * 128 + mf * 16 + lg * 4;
#pragma unroll
    for (int nf = 0; nf < 4; ++nf) {
      long c = n0 + wn * 64 + nf * 16 + l15;
      float bvv = bias ? bias[c] : 0.f;
#pragma unroll
      for (int j = 0; j < 4; ++j) {
        float v = acc[mf][nf][j] + bvv;
        if (WRITE_BF16)
          ((unsigned short*)Cout)[(r0 + j) * ldc + c] = f2bf(v);
        else
          ((float*)Cout)[(r0 + j) * ldc + c] = v;
      }
    }
  }
}

// ---------------- stage 2: l2norm Q/K, tgt = LN(V-K) part, eta ----------------
__global__ __launch_bounds__(256) void stage2(
    const unsigned short* __restrict__ QKVL, const float* __restrict__ tnw,
    const float* __restrict__ tnb, unsigned short* __restrict__ XQn,
    unsigned short* __restrict__ XKn, unsigned short* __restrict__ TGT,
    float* __restrict__ eta_buf) {
  int wid = threadIdx.x >> 6, lane = threadIdx.x & 63;
  long idx = (long)blockIdx.x * 4 + wid;
  long t = idx >> 4;
  int h = (int)(idx & 15);
  size_t base = (size_t)t * 3328;
  float q = bf2f(QKVL[base + h * 64 + lane]);
  float k = bf2f(QKVL[base + 1024 + h * 64 + lane]);
  float v = bf2f(QKVL[base + 2048 + h * 64 + lane]);
  float sq = q * q, sk = k * k;
#pragma unroll
  for (int o = 1; o < 64; o <<= 1) {
    sq += __shfl_xor(sq, o);
    sk += __shfl_xor(sk, o);
  }
  float qn = q / fmaxf(sqrtf(sq), 1e-12f);
  float kn = k / fmaxf(sqrtf(sk), 1e-12f);
  float d = v - kn;
  float s1 = d, s2 = d * d;
#pragma unroll
  for (int o = 1; o < 64; o <<= 1) {
    s1 += __shfl_xor(s1, o);
    s2 += __shfl_xor(s2, o);
  }
  float mu = s1 * 0.015625f;
  float var1 = fmaxf(s2 - 64.f * mu * mu, 0.f) * (1.f / 63.f);  // ddof=1
  float sd = sqrtf(var1);
  float tgt = tnw[h * 64 + lane] * ((d - mu) / (sd + 1e-5f)) + tnb[h * 64 + lane];
  size_t ob = (size_t)t * 1024 + h * 64 + lane;
  XQn[ob] = f2bf(qn);
  XKn[ob] = f2bf(kn);
  TGT[ob] = f2bf(tgt);
  if (lane == 0) {
    float logit = bf2f(QKVL[base + 3072 + h]);
    float sig = 1.f / (1.f + expf(-logit));
    long bb = t >> 13, l = t & 8191;
    eta_buf[(size_t)(bb * 16 + h) * 8192 + l] = sig * (1.f / 4096.f);
  }
}

// ---------------- stage 3: sequential TTT scan ----------------
// 8 waves role-split, 2 raw barriers/chunk, double-buffered staging,
// single-round fused LN-bwd, register bpart, bst update in phase-2 shadow.
__global__ __launch_bounds__(512, 1) void ttt_scan(
    const unsigned short* __restrict__ XQ, const unsigned short* __restrict__ XK,
    const unsigned short* __restrict__ TG, const float* __restrict__ eta_buf,
    const float* __restrict__ W1, const float* __restrict__ b1,
    const float* __restrict__ tnw, const float* __restrict__ tnb,
    unsigned short* __restrict__ y) {
  const int bh = blockIdx.x;
  const int b = bh >> 4, h = bh & 15;
  const int tid = threadIdx.x;
  const int lane = tid & 63, wid = tid >> 6;
  const bool isA = wid < 4;
  const int q = wid & 3;
  const int l15 = lane & 15, lg = lane >> 4;

  __shared__ __align__(16) unsigned short xq_s[2][64 * 72];
  __shared__ __align__(16) unsigned short tg_s[2][64 * 72];
  __shared__ __align__(16) unsigned short xk_s[2][64 * 72];
  __shared__ __align__(16) unsigned short gc_s[64 * 72];
  __shared__ __align__(16) unsigned short gradT[64 * 72];
  __shared__ __align__(16) unsigned short WT_b[2][64 * 72];
  __shared__ __align__(16) unsigned short xkTe[64 * 68];
  __shared__ float eta_s[2][64];
  __shared__ float bpart[4][64];

  const size_t tokb = (size_t)b * 8192;
  const int col0 = h * 64;
  const int rr_ = q * 16 + (lane >> 3);
  const int c8_ = (lane & 7) * 8;

  short8 pA0[2], pA1[2], pB0[2];
  float peta = 0.f;
  float bstv[4], gwv[4], gbv[4], P0 = 0.f;
  f32x4 Wreg[4];

  if (isA) {
#pragma unroll
    for (int n = 0; n < 4; ++n) {
      int e = n * 16 + l15;
      bstv[n] = b1[h * 64 + e];
      gwv[n] = tnw[h * 64 + e];
      gbv[n] = tnb[h * 64 + e];
      P0 += gwv[n] * gwv[n];
    }
    P0 = dpp16_sum(P0);
#pragma unroll
    for (int j = 0; j < 2; ++j) {
      size_t g = (tokb + rr_ + j * 8) * 1024 + col0 + c8_;
      pA0[j] = *(const short8*)&XQ[g];
      pA1[j] = *(const short8*)&TG[g];
    }
#pragma unroll
    for (int j = 0; j < 2; ++j) {
      int rr = rr_ + j * 8;
      *(short8*)&xq_s[0][rr * 72 + c8_] = pA0[j];
      *(short8*)&tg_s[0][rr * 72 + c8_] = pA1[j];
    }
#pragma unroll
    for (int j = 0; j < 2; ++j) {
      size_t g = (tokb + 64 + rr_ + j * 8) * 1024 + col0 + c8_;
      pA0[j] = *(const short8*)&XQ[g];
      pA1[j] = *(const short8*)&TG[g];
    }
  } else {
#pragma unroll
    for (int j = 0; j < 2; ++j)
      pB0[j] = *(const short8*)&XK[(tokb + rr_ + j * 8) * 1024 + col0 + c8_];
#pragma unroll
    for (int j = 0; j < 2; ++j)
      *(short8*)&xk_s[0][(rr_ + j * 8) * 72 + c8_] = pB0[j];
#pragma unroll
    for (int j = 0; j < 2; ++j)
      pB0[j] = *(const short8*)&XK[(tokb + 64 + rr_ + j * 8) * 1024 + col0 + c8_];
#pragma unroll
    for (int n = 0; n < 4; ++n)
#pragma unroll
      for (int jj = 0; jj < 4; ++jj) {
        int d = q * 16 + lg * 4 + jj, e = n * 16 + l15;
        float w = W1[h * 4096 + d * 64 + e];
        Wreg[n][jj] = w;
        WT_b[0][e * 72 + d] = f2bf(w);
      }
    if (wid == 4) {
      eta_s[0][lane] = eta_buf[(size_t)bh * 8192 + lane];
      peta = eta_buf[(size_t)bh * 8192 + 64 + lane];
    }
  }
  __syncthreads();

  for (int nc = 0; nc < 128; ++nc) {
    const int p = nc & 1;
    const unsigned short* WTc = WT_b[p];
    unsigned short* WTn = WT_b[p ^ 1];

    // ================= phase 1 =================
    if (isA) {
      // pre-read fragments, tgt, eta
      short8 a_xk[2], b_w[2][4];
#pragma unroll
      for (int kk = 0; kk < 2; ++kk) {
        const int ko = kk * 32 + lg * 8;
        a_xk[kk] = *(const short8*)&xk_s[p][(q * 16 + l15) * 72 + ko];
#pragma unroll
        for (int n = 0; n < 4; ++n)
          b_w[kk][n] = *(const short8*)&WTc[(n * 16 + l15) * 72 + ko];
      }
      float tval[4][4];
#pragma unroll
      for (int j = 0; j < 4; ++j) {
        const int r = q * 16 + lg * 4 + j;
#pragma unroll
        for (int n = 0; n < 4; ++n)
          tval[j][n] = bf2f(tg_s[p][r * 72 + n * 16 + l15]);
      }
      float etar[4];
#pragma unroll
      for (int j = 0; j < 4; ++j) etar[j] = eta_s[p][q * 16 + lg * 4 + j];

      f32x4 accZ[4];
#pragma unroll
      for (int n = 0; n < 4; ++n)
        accZ[n] = (f32x4){bstv[n], bstv[n], bstv[n], bstv[n]};
      __builtin_amdgcn_s_setprio(1);
#pragma unroll
      for (int kk = 0; kk < 2; ++kk)
#pragma unroll
        for (int n = 0; n < 4; ++n)
          accZ[n] = __builtin_amdgcn_mfma_f32_16x16x32_bf16(a_xk[kk], b_w[kk][n],
                                                            accZ[n], 0, 0, 0);
      __builtin_amdgcn_s_setprio(0);

      // staging copies + next prefetch (MFMA shadow)
      if (nc + 1 < 128) {
#pragma unroll
        for (int j = 0; j < 2; ++j) {
          int rr = rr_ + j * 8;
          *(short8*)&xq_s[p ^ 1][rr * 72 + c8_] = pA0[j];
          *(short8*)&tg_s[p ^ 1][rr * 72 + c8_] = pA1[j];
        }
      }
      if (nc + 2 < 128) {
#pragma unroll
        for (int j = 0; j < 2; ++j) {
          size_t g = (tokb + (nc + 2) * 64 + rr_ + j * 8) * 1024 + col0 + c8_;
          pA0[j] = *(const short8*)&XQ[g];
          pA1[j] = *(const short8*)&TG[g];
        }
      }

      // LN-l2 backward: single fused reduction round (6 parallel sums)
      float grv[4][4];
      float bl[4] = {0.f, 0.f, 0.f, 0.f};
#pragma unroll
      for (int j = 0; j < 4; ++j) {
        float z[4], cn[4];
        float a1 = 0.f, a2 = 0.f, p1 = 0.f, p2 = 0.f, q0 = 0.f, q1 = 0.f;
#pragma unroll
        for (int n = 0; n < 4; ++n) {
          z[n] = accZ[n][j];
          float g = gwv[n];
          float g2 = g * g;
          cn[n] = g * (gbv[n] - tval[j][n]);
          a1 += z[n];
          a2 += z[n] * z[n];
          p1 += g2 * z[n];
          p2 += g2 * z[n] * z[n];
          q0 += cn[n];
          q1 += cn[n] * z[n];
        }
        a1 = dpp16_sum(a1);
        a2 = dpp16_sum(a2);
        p1 = dpp16_sum(p1);
        p2 = dpp16_sum(p2);
        q0 = dpp16_sum(q0);
        q1 = dpp16_sum(q1);
        float mu = a1 * 0.015625f;
        float var = a2 * 0.015625f - mu * mu;
        float rstd = rsqrtf(var + 1e-6f);
        float S3 = rstd * (p1 - mu * P0) + q0;
        float S4 = rstd * rstd * (p2 - 2.f * mu * p1 + mu * mu * P0) +
                   rstd * (q1 - mu * q0);
        float rs64 = rstd * 0.015625f;
#pragma unroll
        for (int n = 0; n < 4; ++n) {
          float xh = (z[n] - mu) * rstd;
          float gx = gwv[n] * gwv[n] * xh + cn[n];
          float gr = (64.f * gx - S3 - xh * S4) * rs64;
          grv[n][j] = gr;
          bl[n] += etar[j] * gr;
        }
      }
#pragma unroll
      for (int n = 0; n < 4; ++n) {
        us4 pk = {f2bf(grv[n][0]), f2bf(grv[n][1]), f2bf(grv[n][2]),
                  f2bf(grv[n][3])};
        *(us4*)&gradT[(n * 16 + l15) * 72 + q * 16 + lg * 4] = pk;
        float s = bl[n];
        s += __shfl_xor(s, 16);
        s += __shfl_xor(s, 32);
        if (lg == 0) bpart[q][n * 16 + l15] = s;
      }
    } else {
      short8 a_xq[2], b_k[2][4];
#pragma unroll
      for (int kk = 0; kk < 2; ++kk) {
        const int ko = kk * 32 + lg * 8;
        a_xq[kk] = *(const short8*)&xq_s[p][(q * 16 + l15) * 72 + ko];
#pragma unroll
        for (int n = 0; n < 4; ++n)
          b_k[kk][n] = *(const short8*)&xk_s[p][(n * 16 + l15) * 72 + ko];
      }
      f32x4 accA[4];
#pragma unroll
      for (int n = 0; n < 4; ++n) accA[n] = (f32x4){0.f, 0.f, 0.f, 0.f};
      __builtin_amdgcn_s_setprio(1);
#pragma unroll
      for (int kk = 0; kk < 2; ++kk)
#pragma unroll
        for (int n = 0; n < 4; ++n)
          accA[n] = __builtin_amdgcn_mfma_f32_16x16x32_bf16(a_xq[kk], b_k[kk][n],
                                                            accA[n], 0, 0, 0);
      __builtin_amdgcn_s_setprio(0);

      // xkTe[d][c] = -eta[c]*xk[c][d]  (stride 68)
#pragma unroll
      for (int it = 0; it < 4; ++it) {
        int c0 = q * 16 + it * 4;
        us4 pk;
#pragma unroll
        for (int u = 0; u < 4; ++u)
          pk[u] = f2bf(-eta_s[p][c0 + u] * bf2f(xk_s[p][(c0 + u) * 72 + lane]));
        *(us4*)&xkTe[lane * 68 + c0] = pk;
      }

      if (nc + 1 < 128) {
#pragma unroll
        for (int j = 0; j < 2; ++j)
          *(short8*)&xk_s[p ^ 1][(rr_ + j * 8) * 72 + c8_] = pB0[j];
        if (wid == 4) eta_s[p ^ 1][lane] = peta;
      }
      if (nc + 2 < 128) {
#pragma unroll
        for (int j = 0; j < 2; ++j)
          pB0[j] = *(const short8*)
              &XK[(tokb + (nc + 2) * 64 + rr_ + j * 8) * 1024 + col0 + c8_];
        if (wid == 4) peta = eta_buf[(size_t)bh * 8192 + (nc + 2) * 64 + lane];
      }

#pragma unroll
      for (int j = 0; j < 4; ++j) {
        const int r = q * 16 + lg * 4 + j;
#pragma unroll
        for (int n = 0; n < 4; ++n) {
          int cj = n * 16 + l15;
          float v = (cj <= r) ? (-eta_s[p][cj] * (1.f + accA[n][j])) : 0.f;
          gc_s[r * 72 + cj] = f2bf(v);
        }
      }
    }
    barrier_fast();  // X

    // ================= phase 2 =================
    if (isA) {
      short8 a_xq[2], a_gc[2], b_w[2][4], b_g[2][4];
#pragma unroll
      for (int kk = 0; kk < 2; ++kk) {
        const int ko = kk * 32 + lg * 8;
        a_xq[kk] = *(const short8*)&xq_s[p][(q * 16 + l15) * 72 + ko];
        a_gc[kk] = *(const short8*)&gc_s[(q * 16 + l15) * 72 + ko];
#pragma unroll
        for (int n = 0; n < 4; ++n) {
          b_w[kk][n] = *(const short8*)&WTc[(n * 16 + l15) * 72 + ko];
          b_g[kk][n] = *(const short8*)&gradT[(n * 16 + l15) * 72 + ko];
        }
      }
      f32x4 accZb[4];
#pragma unroll
      for (int n = 0; n < 4; ++n)
        accZb[n] = (f32x4){bstv[n], bstv[n], bstv[n], bstv[n]};
      __builtin_amdgcn_s_setprio(1);
#pragma unroll
      for (int kk = 0; kk < 2; ++kk)
#pragma unroll
        for (int n = 0; n < 4; ++n) {
          accZb[n] = __builtin_amdgcn_mfma_f32_16x16x32_bf16(a_xq[kk], b_w[kk][n],
                                                             accZb[n], 0, 0, 0);
          accZb[n] = __builtin_amdgcn_mfma_f32_16x16x32_bf16(a_gc[kk], b_g[kk][n],
                                                             accZb[n], 0, 0, 0);
        }
      __builtin_amdgcn_s_setprio(0);

      // b update in MFMA shadow (for next chunk)
#pragma unroll
      for (int n = 0; n < 4; ++n) {
        int e = n * 16 + l15;
        bstv[n] -= bpart[0][e] + bpart[1][e] + bpart[2][e] + bpart[3][e];
      }

#pragma unroll
      for (int j = 0; j < 4; ++j) {
        const int r = q * 16 + lg * 4 + j;
        float z[4], s1 = 0.f, s2 = 0.f;
#pragma unroll
        for (int n = 0; n < 4; ++n) {
          z[n] = accZb[n][j];
          s1 += z[n];
          s2 += z[n] * z[n];
        }
        s1 = dpp16_sum(s1);
        s2 = dpp16_sum(s2);
        float mu = s1 * 0.015625f;
        float var = s2 * 0.015625f - mu * mu;
        float rstd = rsqrtf(var + 1e-6f);
        size_t gbase = (tokb + nc * 64 + r) * 1024 + col0;
#pragma unroll
        for (int n = 0; n < 4; ++n) {
          int e = n * 16 + l15;
          float ov = bf2f(xq_s[p][r * 72 + e]) + gwv[n] * ((z[n] - mu) * rstd) + gbv[n];
          y[gbase + e] = f2bf(ov);
        }
      }
    } else {
      short8 a_ke[2], b_g[2][4];
#pragma unroll
      for (int kk = 0; kk < 2; ++kk) {
        const int ko = kk * 32 + lg * 8;
        short4v lo = *(const short4v*)&xkTe[(q * 16 + l15) * 68 + ko];
        short4v hi = *(const short4v*)&xkTe[(q * 16 + l15) * 68 + ko + 4];
        a_ke[kk] = (short8){lo[0], lo[1], lo[2], lo[3], hi[0], hi[1], hi[2], hi[3]};
#pragma unroll
        for (int n = 0; n < 4; ++n)
          b_g[kk][n] = *(const short8*)&gradT[(n * 16 + l15) * 72 + ko];
      }
      f32x4 accW[4];
#pragma unroll
      for (int n = 0; n < 4; ++n) accW[n] = Wreg[n];
      __builtin_amdgcn_s_setprio(1);
#pragma unroll
      for (int kk = 0; kk < 2; ++kk)
#pragma unroll
        for (int n = 0; n < 4; ++n)
          accW[n] = __builtin_amdgcn_mfma_f32_16x16x32_bf16(a_ke[kk], b_g[kk][n],
                                                            accW[n], 0, 0, 0);
      __builtin_amdgcn_s_setprio(0);
#pragma unroll
      for (int n = 0; n < 4; ++n) {
        Wreg[n] = accW[n];
        us4 pk = {f2bf(accW[n][0]), f2bf(accW[n][1]), f2bf(accW[n][2]),
                  f2bf(accW[n][3])};
        *(us4*)&WTn[(n * 16 + l15) * 72 + q * 16 + lg * 4] = pk;
      }
    }
    barrier_fast();  // Y
  }
}

// ---------------- stage 4: post layernorm over D=1024 (bf16 in) ----------------
__global__ __launch_bounds__(256) void postnorm(
    const unsigned short* __restrict__ yv, const float* __restrict__ pw,
    const float* __restrict__ pb, unsigned short* __restrict__ yn) {
  int t = blockIdx.x;
  int tid = threadIdx.x, lane = tid & 63, wid = tid >> 6;
  us4 v4 = *(const us4*)&yv[(size_t)t * 1024 + tid * 4];
  float v[4];
  float s1 = 0.f, s2 = 0.f;
#pragma unroll
  for (int u = 0; u < 4; ++u) {
    v[u] = bf2f(v4[u]);
    s1 += v[u];
    s2 += v[u] * v[u];
  }
#pragma unroll
  for (int o = 1; o < 64; o <<= 1) {
    s1 += __shfl_xor(s1, o);
    s2 += __shfl_xor(s2, o);
  }
  __shared__ float r1[4], r2[4];
  if (lane == 0) {
    r1[wid] = s1;
    r2[wid] = s2;
  }
  __syncthreads();
  s1 = r1[0] + r1[1] + r1[2] + r1[3];
  s2 = r2[0] + r2[1] + r2[2] + r2[3];
  float mu = s1 * (1.f / 1024.f);
  float var = s2 * (1.f / 1024.f) - mu * mu;
  float rstd = rsqrtf(var + 1e-6f);
  int c = tid * 4;
  us4 o4;
#pragma unroll
  for (int u = 0; u < 4; ++u)
    o4[u] = f2bf(pw[c + u] * ((v[u] - mu) * rstd) + pb[c + u]);
  *(us4*)&yn[(size_t)t * 1024 + c] = o4;
}

// ---------------------------------------------------------------------------
extern "C" void kernel_launch(void* const* d_in, const int* in_sizes, int n_in,
                              void* d_out, int out_size, void* d_ws,
                              size_t ws_size, hipStream_t stream) {
  const float* hs  = (const float*)d_in[0];
  const float* wqw = (const float*)d_in[1];
  const float* wqb = (const float*)d_in[2];
  const float* wkw = (const float*)d_in[3];
  const float* wkb = (const float*)d_in[4];
  const float* wvw = (const float*)d_in[5];
  const float* wvb = (const float*)d_in[6];
  const float* wow = (const float*)d_in[7];
  const float* wob = (const float*)d_in[8];
  const float* tnw = (const float*)d_in[9];
  const float* tnb = (const float*)d_in[10];
  const float* lrw = (const float*)d_in[11];
  const float* lrb = (const float*)d_in[12];
  const float* W1  = (const float*)d_in[13];
  const float* b1  = (const float*)d_in[14];
  const float* pnw = (const float*)d_in[15];
  const float* pnb = (const float*)d_in[16];

  // workspace: hs_bf (→XQn alias) | Wcat | biasc | wo_bf | QKVL (→ybf,ynorm) |
  //            XKn | TGT | eta
  const size_t OFF_WCAT  = 67108864;
  const size_t OFF_BIASC = OFF_WCAT + 6815744;
  const size_t OFF_WOBF  = OFF_BIASC + 16384;
  const size_t OFF_QKVL  = OFF_WOBF + 2097152;
  const size_t OFF_XK    = OFF_QKVL + 218103808;
  const size_t OFF_TGT   = OFF_XK + 67108864;
  const size_t OFF_ETA   = OFF_TGT + 67108864;
  const size_t NEEDED    = OFF_ETA + 2097152;
  if (ws_size < NEEDED) return;

  char* ws = (char*)d_ws;
  unsigned short* hs_bf = (unsigned short*)ws;
  unsigned short* XQn   = (unsigned short*)ws;                        // alias
  unsigned short* Wcat  = (unsigned short*)(ws + OFF_WCAT);
  float* biasc          = (float*)(ws + OFF_BIASC);
  unsigned short* wo_bf = (unsigned short*)(ws + OFF_WOBF);
  unsigned short* QKVL  = (unsigned short*)(ws + OFF_QKVL);
  unsigned short* ybf   = (unsigned short*)(ws + OFF_QKVL);           // alias
  unsigned short* ynorm = (unsigned short*)(ws + OFF_QKVL + 67108864);// alias
  unsigned short* XKn   = (unsigned short*)(ws + OFF_XK);
  unsigned short* TGT   = (unsigned short*)(ws + OFF_TGT);
  float* eta_buf        = (float*)(ws + OFF_ETA);

  cvt_f32_bf16<<<32768, 256, 0, stream>>>(hs, hs_bf, 33554432L);
  build_wcat<<<13312, 256, 0, stream>>>(wqw, wkw, wvw, lrw, wqb, wkb, wvb, lrb,
                                        Wcat, biasc);
  cvt_f32_bf16<<<1024, 256, 0, stream>>>(wow, wo_bf, 1048576L);
  gemm256<1><<<1664, 512, 0, stream>>>(hs_bf, Wcat, biasc, QKVL,
                                       32768L, 3328L, 1024L, 13, 3328L);
  stage2<<<131072, 256, 0, stream>>>(QKVL, tnw, tnb, XQn, XKn, TGT, eta_buf);
  ttt_scan<<<64, 512, 0, stream>>>(XQn, XKn, TGT, eta_buf, W1, b1, tnw, tnb, ybf);
  postnorm<<<32768, 256, 0, stream>>>(ybf, pnw, pnb, ynorm);
  gemm256<0><<<512, 512, 0, stream>>>(ynorm, wo_bf, wob, d_out,
                                      32768L, 1024L, 1024L, 4, 1024L);
}